// Round 1
// baseline (243.421 us; speedup 1.0000x reference)
//
#include <hip/hip_runtime.h>

// CRF loss, B=1024, T=512, K=32.
// Mapping: block = 64 threads = 1 wave = 2 sequences (one per 32-lane half).
// Lane j (within half) owns state j: alpha[j], and E-column E[i][j]=exp(trans[i][j])
// in 32 VGPRs. Per step: e = exp(alpha - m) broadcast via LDS, dot vs Ecol in
// registers, new = log(s) + m + emit. Path scores fused into the same sweep.

#define T_ 512
#define K_ 32

#define SWZ(x, off) __int_as_float(__builtin_amdgcn_ds_swizzle(__float_as_int(x), (off)))

__global__ __launch_bounds__(64) void crf_kernel(
    const int* __restrict__ labels,
    const float* __restrict__ y_pred,
    const float* __restrict__ trans,
    const float* __restrict__ mask,
    float* __restrict__ out)
{
    __shared__ float sh_trans[K_ * K_];
    __shared__ float sh_e[2][64];

    const int lane = threadIdx.x;          // 0..63
    const int half = lane >> 5;            // 0 or 1
    const int j    = lane & 31;            // state index
    const int seq  = blockIdx.x * 2 + half;

    // stage raw trans for the trans-score gather
    for (int idx = lane; idx < K_ * K_; idx += 64) sh_trans[idx] = trans[idx];

    // E-column for this lane: E[i][j] = exp(trans[i][j]), i = 0..31
    float Ecol[K_];
#pragma unroll
    for (int i = 0; i < K_; ++i) Ecol[i] = __expf(trans[i * K_ + j]);

    const float* yp = y_pred + (size_t)seq * T_ * K_;
    const int*   lb = labels + (size_t)seq * T_;
    const float* mk = mask   + (size_t)seq * T_;

    // t = 0 init
    float alpha     = yp[j];
    int   lab_prev  = lb[0];
    float mask_prev = mk[0];
    float ps = (j == lab_prev) ? alpha * mask_prev : 0.0f;   // point score partial
    float ts = 0.0f;                                         // trans score (same in all lanes of half)

    // prefetch t = 1
    float emit_n = yp[K_ + j];
    int   lab_n  = lb[1];
    float mask_n = mk[1];

    __syncthreads();   // sh_trans ready

    for (int t = 1; t < T_; ++t) {
        const float emit = emit_n;
        const int   labv = lab_n;
        const float mv   = mask_n;

        // prefetch t+1 (clamped; last iteration's prefetch is discarded)
        const int tn = (t + 1 < T_) ? (t + 1) : (T_ - 1);
        emit_n = yp[tn * K_ + j];
        lab_n  = lb[tn];
        mask_n = mk[tn];

        // stability shift: alpha of state 0 of this half (spread is bounded)
        const float m = SWZ(alpha, 0x0000);          // bcast lane 0 per 32-group
        const float e = __expf(alpha - m);

        sh_e[t & 1][lane] = e;
        __syncthreads();

        const float4* e4 = (const float4*)&sh_e[t & 1][half * K_];
        float s0 = 0.f, s1 = 0.f, s2 = 0.f, s3 = 0.f;
#pragma unroll
        for (int p = 0; p < 8; ++p) {
            const float4 v = e4[p];
            s0 = fmaf(v.x, Ecol[4 * p + 0], s0);
            s1 = fmaf(v.y, Ecol[4 * p + 1], s1);
            s2 = fmaf(v.z, Ecol[4 * p + 2], s2);
            s3 = fmaf(v.w, Ecol[4 * p + 3], s3);
        }
        const float s = (s0 + s1) + (s2 + s3);

        const float newv = __logf(s) + m + emit;
        alpha = mv * newv + (1.0f - mv) * alpha;     // reference's float-mask blend

        // fused path scores
        ps += (j == labv) ? emit * mv : 0.0f;
        ts  = fmaf(sh_trans[lab_prev * K_ + labv], mv * mask_prev, ts);

        lab_prev  = labv;
        mask_prev = mv;
    }

    // final logsumexp over this half's 32 alphas + point-score reduction
    float mx = alpha;
    mx = fmaxf(mx, SWZ(mx, 0x041F));
    mx = fmaxf(mx, SWZ(mx, 0x081F));
    mx = fmaxf(mx, SWZ(mx, 0x101F));
    mx = fmaxf(mx, SWZ(mx, 0x201F));
    mx = fmaxf(mx, SWZ(mx, 0x401F));

    float ex = __expf(alpha - mx);
    ex += SWZ(ex, 0x041F);
    ex += SWZ(ex, 0x081F);
    ex += SWZ(ex, 0x101F);
    ex += SWZ(ex, 0x201F);
    ex += SWZ(ex, 0x401F);

    ps += SWZ(ps, 0x041F);
    ps += SWZ(ps, 0x081F);
    ps += SWZ(ps, 0x101F);
    ps += SWZ(ps, 0x201F);
    ps += SWZ(ps, 0x401F);

    if (j == 0) {
        const float log_norm = mx + __logf(ex);
        out[seq] = log_norm - (ps + ts);
    }
}

extern "C" void kernel_launch(void* const* d_in, const int* in_sizes, int n_in,
                              void* d_out, int out_size, void* d_ws, size_t ws_size,
                              hipStream_t stream) {
    const int*   labels = (const int*)  d_in[0];
    const float* y_pred = (const float*)d_in[1];
    const float* trans  = (const float*)d_in[2];
    const float* mask   = (const float*)d_in[3];
    float* out = (float*)d_out;

    // B = 1024 sequences, 2 per block
    crf_kernel<<<512, 64, 0, stream>>>(labels, y_pred, trans, mask, out);
}

// Round 2
// 203.468 us; speedup vs baseline: 1.1964x; 1.1964x over previous
//
#include <hip/hip_runtime.h>

// CRF loss, B=1024, T=512, K=32.
// One wave (64 threads) per 2 sequences: lanes 0-31 = states of seq A,
// lanes 32-63 = seq B. Linear-domain forward recurrence:
//   p_j <- (sum_i p_i * E[i][j]) * exp(emit_j),  E = exp(trans) in 32 VGPRs.
// alpha = S + log p; per-step renorm by lane-0's p (c comes free from the
// first LDS float4 read; 1/c and log(c) run in the shadow of the dot).
// exp/log are OFF the recurrence critical path. Emit is prefetched 4 steps
// deep to hide HBM/L3 latency. Labels/mask staged to LDS once. No barrier
// in the loop: single-wave block, DS pipe is in-order per wave.

#define T_ 512
#define K_ 32

#define SWZX(x, m) __int_as_float(__builtin_amdgcn_ds_swizzle(__float_as_int(x), ((m) << 10) | 0x1F))
#define SWZ0(x)    __int_as_float(__builtin_amdgcn_ds_swizzle(__float_as_int(x), 0x0000))

__global__ __launch_bounds__(64) void crf_kernel(
    const int* __restrict__ labels,
    const float* __restrict__ y_pred,
    const float* __restrict__ trans,
    const float* __restrict__ mask,
    float* __restrict__ out)
{
    __shared__ float sh_trans[K_ * K_];
    __shared__ __align__(16) float sh_p[64];
    __shared__ int   sh_lab[2][T_];
    __shared__ float sh_mk[2][T_];

    const int lane = threadIdx.x;          // 0..63
    const int half = lane >> 5;            // 0 or 1
    const int j    = lane & 31;            // state index
    const int seq  = blockIdx.x * 2 + half;

    const float* yp = y_pred + (size_t)seq * T_ * K_;

    // one-time staging: trans, labels, mask -> LDS
    for (int idx = lane; idx < K_ * K_; idx += 64) sh_trans[idx] = trans[idx];
    {
        const int*   lbA = labels + (size_t)(blockIdx.x * 2) * T_;
        const int*   lbB = lbA + T_;
        const float* mkA = mask + (size_t)(blockIdx.x * 2) * T_;
        const float* mkB = mkA + T_;
        for (int idx = lane; idx < T_; idx += 64) {
            sh_lab[0][idx] = lbA[idx];
            sh_lab[1][idx] = lbB[idx];
            sh_mk[0][idx]  = mkA[idx];
            sh_mk[1][idx]  = mkB[idx];
        }
    }

    // E-column for this lane: E[i][j] = exp(trans[i][j])
    float Ecol[K_];
#pragma unroll
    for (int i = 0; i < K_; ++i) Ecol[i] = __expf(trans[i * K_ + j]);

    __syncthreads();   // staging done (one-time cost)

    // t = 0 init: alpha0 = yp[0][j];  p = exp(alpha0 - m0), S = m0
    const float a0 = yp[j];
    const float m0 = SWZ0(a0);
    float p = __expf(a0 - m0);
    float S = m0;

    int   lab_prev  = sh_lab[half][0];
    float mask_prev = sh_mk[half][0];
    float ps = (j == lab_prev) ? a0 * mask_prev : 0.0f;   // point score partial
    float ts = 0.0f;                                      // trans score

    const float4* e4 = (const float4*)&sh_p[half * K_];

    auto step = [&](int t, float em) {
        // write first: it gates the 8 broadcast reads (in-order DS pipe)
        sh_p[lane] = p;
        const int   lab = sh_lab[half][t];   // uniform per half; needed late
        const float mv  = sh_mk[half][t];
        const float eem = __expf(em);        // needed only at the end -> hidden

        float4 v0 = e4[0];
        const float c = v0.x;                // lane-0's p: free renorm scalar
        float s0 = v0.x * Ecol[0];
        float s1 = v0.y * Ecol[1];
        float s2 = v0.z * Ecol[2];
        float s3 = v0.w * Ecol[3];
#pragma unroll
        for (int q = 1; q < 8; ++q) {
            const float4 v = e4[q];
            s0 = fmaf(v.x, Ecol[4 * q + 0], s0);
            s1 = fmaf(v.y, Ecol[4 * q + 1], s1);
            s2 = fmaf(v.z, Ecol[4 * q + 2], s2);
            s3 = fmaf(v.w, Ecol[4 * q + 3], s3);
        }
        const float s = (s0 + s1) + (s2 + s3);

        const float r  = 1.0f / c;           // starts as soon as v0 lands -> hidden
        const float pn = s * (eem * r);      // new alpha, renormalized
        const float po = p * r;              // old alpha, same renorm
        p = (mv != 0.0f) ? pn : po;          // mask is {0,1}; select is exact
        S += __logf(c);                      // off-chain scalar accumulate

        ps += (j == lab) ? em * mv : 0.0f;
        ts  = fmaf(sh_trans[lab_prev * K_ + lab], mv * mask_prev, ts);
        lab_prev  = lab;
        mask_prev = mv;
    };

    // 4-deep emit prefetch pipeline over t = 1..511
    float emA = yp[1 * K_ + j];
    float emB = yp[2 * K_ + j];
    float emC = yp[3 * K_ + j];
    float emD = yp[4 * K_ + j];

    int t = 1;
    for (int chunk = 0; chunk < 126; ++chunk) {   // covers t = 1..504
        step(t + 0, emA); emA = yp[(t + 4) * K_ + j];
        step(t + 1, emB); emB = yp[(t + 5) * K_ + j];
        step(t + 2, emC); emC = yp[(t + 6) * K_ + j];
        step(t + 3, emD); emD = yp[(t + 7) * K_ + j];
        t += 4;
    }
    // epilogue: t = 505..511 (emA..emD hold 505..508 from the last chunk)
    step(505, emA); emA = yp[509 * K_ + j];
    step(506, emB); emB = yp[510 * K_ + j];
    step(507, emC); emC = yp[511 * K_ + j];
    step(508, emD);
    step(509, emA);
    step(510, emB);
    step(511, emC);

    // final: log_norm = S + log(sum_j p_j);  reduce p and ps per 32-lane half
    float sp = p;
    sp += SWZX(sp, 1);
    sp += SWZX(sp, 2);
    sp += SWZX(sp, 4);
    sp += SWZX(sp, 8);
    sp += SWZX(sp, 16);

    ps += SWZX(ps, 1);
    ps += SWZX(ps, 2);
    ps += SWZX(ps, 4);
    ps += SWZX(ps, 8);
    ps += SWZX(ps, 16);

    if (j == 0) {
        out[seq] = S + __logf(sp) - (ps + ts);
    }
}

extern "C" void kernel_launch(void* const* d_in, const int* in_sizes, int n_in,
                              void* d_out, int out_size, void* d_ws, size_t ws_size,
                              hipStream_t stream) {
    const int*   labels = (const int*)  d_in[0];
    const float* y_pred = (const float*)d_in[1];
    const float* trans  = (const float*)d_in[2];
    const float* mask   = (const float*)d_in[3];
    float* out = (float*)d_out;

    crf_kernel<<<512, 64, 0, stream>>>(labels, y_pred, trans, mask, out);
}

// Round 3
// 197.024 us; speedup vs baseline: 1.2355x; 1.0327x over previous
//
#include <hip/hip_runtime.h>

// CRF loss, B=1024, T=512, K=32.
// One wave per 2 sequences (lanes 0-31 = seq A states, 32-63 = seq B).
//
// Phase 1 (parallel): point+trans path scores. No sequential dependence --
// each lane covers 16 timesteps, butterfly-reduce per 32-lane half.
//
// Phase 2 (serial, the wall clock): linear-domain recurrence
//   p_j <- (sum_i p_i * E[i][j]) * exp(emit_j),  E = exp(trans) in 32 VGPRs,
// per-step renorm by lane-0's p (free from the first LDS float4), S += log c
// off-chain. Loop body's ONLY lgkm ops are the p round-trip (1 ds_write +
// 8 ds_read_b128); emit/mask prefetched 4-deep from GLOBAL (vmcnt). No
// barrier: single-wave block, DS pipe is in-order per wave.

#define T_ 512
#define K_ 32

#define SWZX(x, m) __int_as_float(__builtin_amdgcn_ds_swizzle(__float_as_int(x), ((m) << 10) | 0x1F))
#define SWZ0(x)    __int_as_float(__builtin_amdgcn_ds_swizzle(__float_as_int(x), 0x0000))

__global__ __launch_bounds__(64) void crf_kernel(
    const int* __restrict__ labels,
    const float* __restrict__ y_pred,
    const float* __restrict__ trans,
    const float* __restrict__ mask,
    float* __restrict__ out)
{
    __shared__ float sh_trans[K_ * K_];
    __shared__ __align__(16) float sh_p[64];

    const int lane = threadIdx.x;          // 0..63
    const int half = lane >> 5;            // 0 or 1
    const int j    = lane & 31;            // state index / lane-in-half
    const int seq  = blockIdx.x * 2 + half;

    const float* yp = y_pred + (size_t)seq * T_ * K_;
    const int*   lb = labels + (size_t)seq * T_;
    const float* mk = mask   + (size_t)seq * T_;

    for (int idx = lane; idx < K_ * K_; idx += 64) sh_trans[idx] = trans[idx];

    // E-column for this lane: E[i][j] = exp(trans[i][j])
    float Ecol[K_];
#pragma unroll
    for (int i = 0; i < K_; ++i) Ecol[i] = __expf(trans[i * K_ + j]);

    __syncthreads();   // sh_trans staged

    // ---------- Phase 1: path scores (fully parallel over t) ----------
    float sc = 0.0f;
    {
        const int t0 = j * 16;             // 32 lanes x 16 steps = 512
        int   labv[17];
        float mkv[17];
#pragma unroll
        for (int i = 0; i < 17; ++i) {
            const int t = t0 + i;
            if (t < T_) { labv[i] = lb[t]; mkv[i] = mk[t]; }
            else        { labv[i] = 0;     mkv[i] = 0.0f; }
        }
#pragma unroll
        for (int i = 0; i < 16; ++i) {
            const int t = t0 + i;
            sc = fmaf(yp[t * K_ + labv[i]], mkv[i], sc);                       // point
            sc = fmaf(sh_trans[labv[i] * K_ + labv[i + 1]],
                      mkv[i] * mkv[i + 1], sc);                                // trans
        }
        sc += SWZX(sc, 1);
        sc += SWZX(sc, 2);
        sc += SWZX(sc, 4);
        sc += SWZX(sc, 8);
        sc += SWZX(sc, 16);
    }

    // ---------- Phase 2: serial forward recurrence ----------
    const float a0 = yp[j];
    const float m0 = SWZ0(a0);
    float p = __expf(a0 - m0);
    float S = m0;

    const float4* e4 = (const float4*)&sh_p[half * K_];

    auto step = [&](float mv, float em) {
        const float eem = __expf(em);        // needed only at chain end -> hidden
        sh_p[lane] = p;                      // gates the 8 broadcast reads
        const float4 v0 = e4[0];
        const float c = v0.x;                // lane-0's p: renorm scalar, free
        float s0 = v0.x * Ecol[0];
        float s1 = v0.y * Ecol[1];
        float s2 = v0.z * Ecol[2];
        float s3 = v0.w * Ecol[3];
#pragma unroll
        for (int q = 1; q < 8; ++q) {
            const float4 v = e4[q];
            s0 = fmaf(v.x, Ecol[4 * q + 0], s0);
            s1 = fmaf(v.y, Ecol[4 * q + 1], s1);
            s2 = fmaf(v.z, Ecol[4 * q + 2], s2);
            s3 = fmaf(v.w, Ecol[4 * q + 3], s3);
        }
        const float s = (s0 + s1) + (s2 + s3);

        const float r  = 1.0f / c;           // starts when v0 lands -> hidden
        const float pn = s * (eem * r);
        const float po = p * r;
        p = (mv != 0.0f) ? pn : po;          // mask in {0,1}: exact select
        S += __logf(c);                      // off-chain accumulate
    };

    // 4-deep global prefetch (emit + mask) over t = 1..511
    float emA = yp[1 * K_ + j], emB = yp[2 * K_ + j];
    float emC = yp[3 * K_ + j], emD = yp[4 * K_ + j];
    float mvA = mk[1], mvB = mk[2], mvC = mk[3], mvD = mk[4];

    int t = 1;
    for (int chunk = 0; chunk < 126; ++chunk) {   // t = 1..504
        step(mvA, emA); emA = yp[(t + 4) * K_ + j]; mvA = mk[t + 4];
        step(mvB, emB); emB = yp[(t + 5) * K_ + j]; mvB = mk[t + 5];
        step(mvC, emC); emC = yp[(t + 6) * K_ + j]; mvC = mk[t + 6];
        step(mvD, emD); emD = yp[(t + 7) * K_ + j]; mvD = mk[t + 7];
        t += 4;
    }
    // epilogue: regs hold t = 505..508
    step(mvA, emA); emA = yp[509 * K_ + j]; mvA = mk[509];
    step(mvB, emB); emB = yp[510 * K_ + j]; mvB = mk[510];
    step(mvC, emC); emC = yp[511 * K_ + j]; mvC = mk[511];
    step(mvD, emD);
    step(mvA, emA);
    step(mvB, emB);
    step(mvC, emC);

    // ---------- Final: log_norm - (point + trans) ----------
    float sp = p;
    sp += SWZX(sp, 1);
    sp += SWZX(sp, 2);
    sp += SWZX(sp, 4);
    sp += SWZX(sp, 8);
    sp += SWZX(sp, 16);

    if (j == 0) {
        out[seq] = S + __logf(sp) - sc;
    }
}

extern "C" void kernel_launch(void* const* d_in, const int* in_sizes, int n_in,
                              void* d_out, int out_size, void* d_ws, size_t ws_size,
                              hipStream_t stream) {
    const int*   labels = (const int*)  d_in[0];
    const float* y_pred = (const float*)d_in[1];
    const float* trans  = (const float*)d_in[2];
    const float* mask   = (const float*)d_in[3];
    float* out = (float*)d_out;

    crf_kernel<<<512, 64, 0, stream>>>(labels, y_pred, trans, mask, out);
}